// Round 4
// baseline (642.019 us; speedup 1.0000x reference)
//
#include <hip/hip_runtime.h>
#include <hip/hip_bf16.h>
#include <cstddef>
#include <cstdint>

#define T_TOK 1024
#define HDIM  2048
#define NEXP  64
#define IDIM  768
#define TOPK  8

using f32x4 = __attribute__((ext_vector_type(4))) float;
using s16x8 = __attribute__((ext_vector_type(8))) short;

// ---- workspace layout (bytes) ----
static constexpr size_t XBF_OFF = 0;                                   // bf16 X: 4 MiB
static constexpr size_t CNT_OFF = (size_t)T_TOK * HDIM * 2;            // 64 ints
static constexpr size_t OFF_OFF = CNT_OFF + 256;                       // 65 ints
static constexpr size_t TOK_OFF = CNT_OFF + 1024;                      // 64*1024 ints
static constexpr size_t WT_OFF  = TOK_OFF + (size_t)NEXP * T_TOK * 4;  // 64*1024 floats
static constexpr size_t HH_OFF  = WT_OFF  + (size_t)NEXP * T_TOK * 4;  // 8192*768 bf16

__device__ __forceinline__ short f2bf(float f) {
  union { __hip_bfloat16 b; short s; } u;
  u.b = __float2bfloat16(f);
  return u.s;
}
__device__ __forceinline__ float bf2f(short s) {
  union { short s; __hip_bfloat16 b; } u;
  u.s = s;
  return __bfloat162float(u.b);
}

__device__ __forceinline__ void gl_lds16(const void* g, void* l) {
  __builtin_amdgcn_global_load_lds(
      (const __attribute__((address_space(1))) unsigned int*)g,
      (__attribute__((address_space(3))) unsigned int*)l, 16, 0, 0);
}
__device__ __forceinline__ void barrier_raw() {
  asm volatile("" ::: "memory");
  __builtin_amdgcn_s_barrier();
  asm volatile("" ::: "memory");
}
#define WAIT_VM4()   asm volatile("s_waitcnt vmcnt(4)" ::: "memory")
#define WAIT_VM0()   asm volatile("s_waitcnt vmcnt(0)" ::: "memory")
#define WAIT_LGKM0() asm volatile("s_waitcnt lgkmcnt(0)" ::: "memory")

// ---------------- x fp32 -> bf16 ----------------
__global__ __launch_bounds__(256) void convert_x_kernel(
    const float* __restrict__ X, __hip_bfloat16* __restrict__ Xb) {
  const int i = (blockIdx.x * 256 + threadIdx.x) * 8;
  f32x4 a = *(const f32x4*)(X + i);
  f32x4 b = *(const f32x4*)(X + i + 4);
  union { short h[8]; int4 q; } u;
#pragma unroll
  for (int c = 0; c < 4; ++c) { u.h[c] = f2bf(a[c]); u.h[4 + c] = f2bf(b[c]); }
  *(int4*)((char*)Xb + (size_t)i * 2) = u.q;
}

// ---------------- router ----------------
__global__ __launch_bounds__(256) void router_kernel(
    const float* __restrict__ X, const float* __restrict__ GW,
    int* __restrict__ cnt, int* __restrict__ tokl, float* __restrict__ wtl) {
  __shared__ float xs[HDIM];
  __shared__ float lg[NEXP];
  const int t = blockIdx.x;
  const int tid = threadIdx.x;
  const f32x4* xr = (const f32x4*)(X + (size_t)t * HDIM);
#pragma unroll
  for (int i = 0; i < 2; ++i) {
    f32x4 v = xr[tid + i * 256];
    *(f32x4*)&xs[(tid + i * 256) * 4] = v;
  }
  __syncthreads();
  const int wid = tid >> 6, lane = tid & 63;
  for (int ee = 0; ee < 16; ++ee) {
    const int e = wid * 16 + ee;
    const float* g = GW + (size_t)e * HDIM;
    float acc = 0.f;
    for (int i = lane; i < HDIM; i += 64) acc += xs[i] * g[i];
#pragma unroll
    for (int s = 32; s; s >>= 1) acc += __shfl_xor(acc, s);
    if (lane == 0) lg[e] = acc;
  }
  __syncthreads();
  if (tid < 64) {
    const float v = lg[tid];
    float m = v;
#pragma unroll
    for (int s = 32; s; s >>= 1) m = fmaxf(m, __shfl_xor(m, s));
    const float p = expf(v - m);
    float den = p;
#pragma unroll
    for (int s = 32; s; s >>= 1) den += __shfl_xor(den, s);
    float work = p / den;
    float my_v = 0.f; int my_e = 0;
    float topsum = 0.f;
#pragma unroll
    for (int k = 0; k < TOPK; ++k) {
      float mv = work;
#pragma unroll
      for (int s = 32; s; s >>= 1) mv = fmaxf(mv, __shfl_xor(mv, s));
      unsigned long long ball = __ballot(work == mv);
      const int idx = __ffsll(ball) - 1;   // lowest index on ties (matches lax.top_k)
      topsum += mv;
      if (tid == k) { my_v = mv; my_e = idx; }
      if (tid == idx) work = -1.f;
    }
    if (tid < TOPK) {
      const float w = my_v / topsum;
      const int slot = atomicAdd(&cnt[my_e], 1);
      tokl[my_e * T_TOK + slot] = t;
      wtl[my_e * T_TOK + slot] = w;
    }
  }
}

// ---------------- prefix scan ----------------
__global__ void scan_kernel(const int* __restrict__ cnt, int* __restrict__ offs) {
  if (threadIdx.x == 0) {
    int a = 0;
    for (int e = 0; e < NEXP; ++e) { offs[e] = a; a += cnt[e]; }
    offs[NEXP] = a;
  }
}

// ================= gate+up GEMM + SwiGLU =================
// item = (e, nj): 64*8 = 512 uniform items, static 1:1 grid (2 blocks/CU).
// BM=256 (both ti halves), BN=96 (384B DRAM runs), two sequential K-passes
// (gate then up) sharing one acc; raw g parked in Hh between passes.
// Sub-buffer = 16 k-rows: A 8KB + B 8KB(padded from 6KB) = 16KB; 4 sub-bufs.
#define GU_NSUB  128          // 2048/16 per pass
#define GU_NSTEP 64

__global__ __launch_bounds__(256, 2) void gateup_kernel(
    const __hip_bfloat16* __restrict__ Xb,
    const float* __restrict__ WG, const float* __restrict__ WU,
    const int* __restrict__ cnt, const int* __restrict__ offs,
    const int* __restrict__ tokl, const float* __restrict__ wtl,
    __hip_bfloat16* __restrict__ Hh) {
  __shared__ __align__(16) char sL[4 * 16384];
  const int tid  = threadIdx.x;
  const int lane = tid & 63;
  const int wid  = tid >> 6;
  const int m = lane >> 4;
  const int c = lane & 15;
  const int e  = blockIdx.x >> 3;
  const int nj = blockIdx.x & 7;
  const int ne = cnt[e];
  if (ne == 0) return;
  const int nb    = nj * 96;
  const int cbase = offs[e];
  const int tbase = e * T_TOK;
  const int wrow  = (wid >> 1) * 128;
  const int wcolb = (wid & 1) * 48;

  // ---- A staging geometry (per-lane, invariant) ----
  const int ar0 = wid * 64 + (lane >> 1);
  const int ar1 = ar0 + 32;
  const int achk = (lane & 1) ^ ((lane >> 3) & 1);   // k-chunk pre-swizzle
  const int tok0 = tokl[tbase + min(ar0, ne - 1)];
  const int tok1 = tokl[tbase + min(ar1, ne - 1)];
  // ---- B staging geometry ----
  const int bs = lane & 31;
  const int bg = bs ^ wid;                            // 16B-granule pre-swizzle (y = wid)
  const int bcol = (bg < 24) ? bg * 4 : 0;            // clamp pad lanes

  // ---- fragment byte-offsets (loop-invariant) ----
  int aoffs[8];
#pragma unroll
  for (int mi = 0; mi < 8; ++mi) {
    const int row = wrow + mi * 16 + c;
    aoffs[mi] = row * 32 + (((m & 1) ^ ((c >> 2) & 1)) << 4);
  }
  int boffs[8];
#pragma unroll
  for (int j = 0; j < 8; ++j) {
    const int r = (m & 1) * 8 + j;
    const int y = ((m & 1) * 2 + (j >> 2)) & 3;
    const int col = wcolb + c;
    boffs[j] = r * 512 + (((col >> 2) ^ y) << 4) + (col & 3) * 4;
  }

  f32x4 acc[8][3];

  for (int mat = 0; mat < 2; ++mat) {
    const float* WB = (mat ? WU : WG) + (size_t)e * HDIM * IDIM;
    const float* pb0 = WB + (size_t)(wid * 4 + (lane >> 5)) * IDIM + nb + bcol;
    const float* pb1 = pb0 + (size_t)2 * IDIM;
    const __hip_bfloat16* pa0 = Xb + (size_t)tok0 * HDIM + achk * 8;
    const __hip_bfloat16* pa1 = Xb + (size_t)tok1 * HDIM + achk * 8;
#pragma unroll
    for (int i = 0; i < 8; ++i)
#pragma unroll
      for (int n = 0; n < 3; ++n)
#pragma unroll
        for (int r = 0; r < 4; ++r) acc[i][n][r] = 0.f;

    auto stageSub = [&](int sub) {
      const int bb = (sub & 3) * 16384;
      gl_lds16(pa0, sL + bb + wid * 2048);
      gl_lds16(pa1, sL + bb + wid * 2048 + 1024);
      gl_lds16(pb0, sL + bb + 8192 + wid * 2048);
      gl_lds16(pb1, sL + bb + 8192 + wid * 2048 + 1024);
      pa0 += 16; pa1 += 16;
      pb0 += (size_t)16 * IDIM; pb1 += (size_t)16 * IDIM;
    };
    stageSub(0); stageSub(1); stageSub(2);

    for (int s = 0; s < GU_NSTEP; ++s) {
      if (s == GU_NSTEP - 1) { WAIT_VM0(); } else { WAIT_VM4(); }
      barrier_raw();
      const int base0 = ((2 * s) & 3) * 16384;
      const int am = base0 + ((m < 2) ? 0 : 16384);
      s16x8 af[8];
#pragma unroll
      for (int mi = 0; mi < 8; ++mi) af[mi] = *(const s16x8*)(sL + am + aoffs[mi]);
      const int bm = am + 8192;
      s16x8 bf[3];
#pragma unroll
      for (int nf = 0; nf < 3; ++nf) {
        union { short h[8]; s16x8 v; } u;
#pragma unroll
        for (int j = 0; j < 8; ++j)
          u.h[j] = f2bf(*(const float*)(sL + bm + boffs[j] + nf * 64));
        bf[nf] = u.v;
      }
      WAIT_LGKM0();
      __builtin_amdgcn_sched_barrier(0);
      barrier_raw();
      const int k1 = 2 * s + 3, k2 = 2 * s + 4;
      if (k1 < GU_NSUB) stageSub(k1);
      if (k2 < GU_NSUB) stageSub(k2);
#pragma unroll
      for (int mi = 0; mi < 8; ++mi)
#pragma unroll
        for (int nf = 0; nf < 3; ++nf)
          acc[mi][nf] = __builtin_amdgcn_mfma_f32_16x16x32_bf16(af[mi], bf[nf], acc[mi][nf], 0, 0, 0);
    }

    // epilogue
    if (mat == 0) {
      // park raw g in Hh
#pragma unroll
      for (int mi = 0; mi < 8; ++mi) {
        const int rb = wrow + mi * 16 + m * 4;
#pragma unroll
        for (int nf = 0; nf < 3; ++nf) {
          const int colg = nb + wcolb + nf * 16 + c;
#pragma unroll
          for (int rr = 0; rr < 4; ++rr) {
            const int row = rb + rr;
            if (row < ne)
              Hh[(size_t)(cbase + row) * IDIM + colg] = __float2bfloat16(acc[mi][nf][rr]);
          }
        }
      }
    } else {
      // h = silu(g) * u * wt
#pragma unroll
      for (int mi = 0; mi < 8; ++mi) {
        const int rb = wrow + mi * 16 + m * 4;
#pragma unroll
        for (int nf = 0; nf < 3; ++nf) {
          const int colg = nb + wcolb + nf * 16 + c;
#pragma unroll
          for (int rr = 0; rr < 4; ++rr) {
            const int row = rb + rr;
            if (row < ne) {
              __hip_bfloat16* hp = Hh + (size_t)(cbase + row) * IDIM + colg;
              const float g = __bfloat162float(*hp);
              const float uu = acc[mi][nf][rr];
              const float h = (g / (1.f + __expf(-g))) * uu * wtl[tbase + row];
              *hp = __float2bfloat16(h);
            }
          }
        }
      }
    }
  }
}

// ================= down GEMM + scatter =================
// item = (e, nj): 64*16 = 1024 uniform items, 512 blocks x 2 items.
// BM=256, BN=128 (512B DRAM runs), BK sub-buf = 16 i-rows: A 8KB + B 8KB.
#define DN_NSUB  48           // 768/16
#define DN_NSTEP 24

__global__ __launch_bounds__(256, 2) void down_kernel(
    const __hip_bfloat16* __restrict__ Hh, const float* __restrict__ WD,
    const int* __restrict__ cnt, const int* __restrict__ offs,
    const int* __restrict__ tokl, float* __restrict__ Out) {
  __shared__ __align__(16) char sL[4 * 16384];
  const int tid  = threadIdx.x;
  const int lane = tid & 63;
  const int wid  = tid >> 6;
  const int m = lane >> 4;
  const int c = lane & 15;
  const int wrow  = (wid >> 1) * 128;
  const int wcolb = (wid & 1) * 64;

  const int ar0 = wid * 64 + (lane >> 1);
  const int ar1 = ar0 + 32;
  const int achk = (lane & 1) ^ ((lane >> 3) & 1);
  const int bs = lane & 31;
  const int bg = bs ^ wid;

  int aoffs[8];
#pragma unroll
  for (int mi = 0; mi < 8; ++mi) {
    const int row = wrow + mi * 16 + c;
    aoffs[mi] = row * 32 + (((m & 1) ^ ((c >> 2) & 1)) << 4);
  }
  int boffs[8];
#pragma unroll
  for (int j = 0; j < 8; ++j) {
    const int r = (m & 1) * 8 + j;
    const int y = ((m & 1) * 2 + (j >> 2)) & 3;
    const int col = wcolb + c;
    boffs[j] = r * 512 + (((col >> 2) ^ y) << 4) + (col & 3) * 4;
  }

  f32x4 acc[8][4];

  for (int half = 0; half < 2; ++half) {
    const int it = blockIdx.x + half * 512;
    const int e  = it >> 4;
    const int nj = it & 15;
    const int ne = cnt[e];
    if (ne == 0) continue;
    const int nb    = nj * 128;
    const int cbase = offs[e];
    const int tbase = e * T_TOK;

    const float* WB = WD + (size_t)e * IDIM * HDIM;
    const float* pb0 = WB + (size_t)(wid * 4 + (lane >> 5)) * HDIM + nb + bg * 4;
    const float* pb1 = pb0 + (size_t)2 * HDIM;
    const __hip_bfloat16* pa0 = Hh + (size_t)(cbase + min(ar0, ne - 1)) * IDIM + achk * 8;
    const __hip_bfloat16* pa1 = Hh + (size_t)(cbase + min(ar1, ne - 1)) * IDIM + achk * 8;

#pragma unroll
    for (int i = 0; i < 8; ++i)
#pragma unroll
      for (int n = 0; n < 4; ++n)
#pragma unroll
        for (int r = 0; r < 4; ++r) acc[i][n][r] = 0.f;

    auto stageSub = [&](int sub) {
      const int bb = (sub & 3) * 16384;
      gl_lds16(pa0, sL + bb + wid * 2048);
      gl_lds16(pa1, sL + bb + wid * 2048 + 1024);
      gl_lds16(pb0, sL + bb + 8192 + wid * 2048);
      gl_lds16(pb1, sL + bb + 8192 + wid * 2048 + 1024);
      pa0 += 16; pa1 += 16;
      pb0 += (size_t)16 * HDIM; pb1 += (size_t)16 * HDIM;
    };
    stageSub(0); stageSub(1); stageSub(2);

    for (int s = 0; s < DN_NSTEP; ++s) {
      if (s == DN_NSTEP - 1) { WAIT_VM0(); } else { WAIT_VM4(); }
      barrier_raw();
      const int base0 = ((2 * s) & 3) * 16384;
      const int am = base0 + ((m < 2) ? 0 : 16384);
      s16x8 af[8];
#pragma unroll
      for (int mi = 0; mi < 8; ++mi) af[mi] = *(const s16x8*)(sL + am + aoffs[mi]);
      const int bm = am + 8192;
      s16x8 bf[4];
#pragma unroll
      for (int nf = 0; nf < 4; ++nf) {
        union { short h[8]; s16x8 v; } u;
#pragma unroll
        for (int j = 0; j < 8; ++j)
          u.h[j] = f2bf(*(const float*)(sL + bm + boffs[j] + nf * 64));
        bf[nf] = u.v;
      }
      WAIT_LGKM0();
      __builtin_amdgcn_sched_barrier(0);
      barrier_raw();
      const int k1 = 2 * s + 3, k2 = 2 * s + 4;
      if (k1 < DN_NSUB) stageSub(k1);
      if (k2 < DN_NSUB) stageSub(k2);
#pragma unroll
      for (int mi = 0; mi < 8; ++mi)
#pragma unroll
        for (int nf = 0; nf < 4; ++nf)
          acc[mi][nf] = __builtin_amdgcn_mfma_f32_16x16x32_bf16(af[mi], bf[nf], acc[mi][nf], 0, 0, 0);
    }

    // epilogue: fp32 atomic scatter into Out
#pragma unroll
    for (int mi = 0; mi < 8; ++mi) {
      const int rb = wrow + mi * 16 + m * 4;
#pragma unroll
      for (int rr = 0; rr < 4; ++rr) {
        const int row = rb + rr;
        if (row < ne) {
          const int tok = tokl[tbase + row];
          float* op = Out + (size_t)tok * HDIM + nb + wcolb + c;
#pragma unroll
          for (int nf = 0; nf < 4; ++nf)
            atomicAdd(op + nf * 16, acc[mi][nf][rr]);
        }
      }
    }
  }
}

extern "C" void kernel_launch(void* const* d_in, const int* in_sizes, int n_in,
                              void* d_out, int out_size, void* d_ws, size_t ws_size,
                              hipStream_t stream) {
  (void)in_sizes; (void)n_in; (void)ws_size;
  const float* X  = (const float*)d_in[0];
  const float* GW = (const float*)d_in[1];
  const float* WG = (const float*)d_in[2];
  const float* WU = (const float*)d_in[3];
  const float* WD = (const float*)d_in[4];
  float* Out = (float*)d_out;
  char* ws = (char*)d_ws;

  __hip_bfloat16* Xb = (__hip_bfloat16*)(ws + XBF_OFF);
  int*   cnt  = (int*)(ws + CNT_OFF);
  int*   offs = (int*)(ws + OFF_OFF);
  int*   tokl = (int*)(ws + TOK_OFF);
  float* wtl  = (float*)(ws + WT_OFF);
  __hip_bfloat16* Hh = (__hip_bfloat16*)(ws + HH_OFF);

  hipMemsetAsync(ws + CNT_OFF, 0, 1024, stream);
  hipMemsetAsync(d_out, 0, (size_t)out_size * sizeof(float), stream);

  convert_x_kernel<<<(T_TOK * HDIM) / (256 * 8), 256, 0, stream>>>(X, Xb);
  router_kernel<<<T_TOK, 256, 0, stream>>>(X, GW, cnt, tokl, wtl);
  scan_kernel<<<1, 64, 0, stream>>>(cnt, offs);
  gateup_kernel<<<512, 256, 0, stream>>>(Xb, WG, WU, cnt, offs, tokl, wtl, Hh);
  down_kernel<<<512, 256, 0, stream>>>(Hh, WD, cnt, offs, tokl, Out);
}